// Round 2
// baseline (209.317 us; speedup 1.0000x reference)
//
#include <hip/hip_runtime.h>

#define HW (512 * 512)
#define NBATCH 64
#define BLOCKS_PER_BATCH 32
#define NTHREADS 256
#define PIX_PER_BLOCK (HW / BLOCKS_PER_BATCH)   // 8192
#define NITER (PIX_PER_BLOCK / (NTHREADS * 4))  // 8

// Fused: streaming partial sums + last-block-per-batch finalize.
// Cross-block visibility uses AGENT-scope atomics (per-XCD L2s are not
// coherent; agent-scope ops go through the device coherence point).
__global__ __launch_bounds__(NTHREADS, 8) void fused_kernel(
    const float* __restrict__ Y,      // (B, HW, 3)
    const float* __restrict__ C,      // (B, 2, HW)
    const float* __restrict__ M_ref,  // (B, 3, 2)
    const float* __restrict__ sigma_sq,
    const float* __restrict__ lambda_sq,
    float* __restrict__ ws,           // (B*BLOCKS_PER_BATCH, 9) partials
    unsigned int* __restrict__ cnt,   // (B) arrival counters, memset to 0 per call
    float* __restrict__ out)          // [0:384) out_mean, [384:640) out_var
{
    const int blk = blockIdx.x;
    const int b  = blk / BLOCKS_PER_BATCH;
    const int cb = blk % BLOCKS_PER_BATCH;
    const int tid = threadIdx.x;

    const float* __restrict__ C0 = C + (size_t)b * 2 * HW + (size_t)cb * PIX_PER_BLOCK;
    const float* __restrict__ C1 = C0 + HW;
    const float* __restrict__ Yb = Y + (size_t)b * HW * 3 + (size_t)cb * PIX_PER_BLOCK * 3;

    float g00 = 0.f, g01 = 0.f, g11 = 0.f;
    float y00 = 0.f, y01 = 0.f;
    float y10 = 0.f, y11 = 0.f;
    float y20 = 0.f, y21 = 0.f;

#pragma unroll
    for (int it = 0; it < NITER; ++it) {
        const int p = (it * NTHREADS + tid) * 4;            // pixel group base
        const float4 c0 = *(const float4*)(C0 + p);
        const float4 c1 = *(const float4*)(C1 + p);
        const float4* yv = (const float4*)(Yb + (size_t)p * 3);
        const float4 ya  = yv[0];
        const float4 yb4 = yv[1];
        const float4 yc4 = yv[2];

        g00 += c0.x*c0.x + c0.y*c0.y + c0.z*c0.z + c0.w*c0.w;
        g01 += c0.x*c1.x + c0.y*c1.y + c0.z*c1.z + c0.w*c1.w;
        g11 += c1.x*c1.x + c1.y*c1.y + c1.z*c1.z + c1.w*c1.w;

        // pixel triples: p0:(ya.x,ya.y,ya.z) p1:(ya.w,yb4.x,yb4.y)
        //                p2:(yb4.z,yb4.w,yc4.x) p3:(yc4.y,yc4.z,yc4.w)
        y00 += ya.x*c0.x + ya.w*c0.y + yb4.z*c0.z + yc4.y*c0.w;
        y01 += ya.x*c1.x + ya.w*c1.y + yb4.z*c1.z + yc4.y*c1.w;
        y10 += ya.y*c0.x + yb4.x*c0.y + yb4.w*c0.z + yc4.z*c0.w;
        y11 += ya.y*c1.x + yb4.x*c1.y + yb4.w*c1.z + yc4.z*c1.w;
        y20 += ya.z*c0.x + yb4.y*c0.y + yc4.x*c0.z + yc4.w*c0.w;
        y21 += ya.z*c1.x + yb4.y*c1.y + yc4.x*c1.z + yc4.w*c1.w;
    }

    // wave butterfly reduce the 9 accumulators
    float v[9] = {g00, g01, g11, y00, y01, y10, y11, y20, y21};
#pragma unroll
    for (int k = 0; k < 9; ++k) {
#pragma unroll
        for (int off = 32; off > 0; off >>= 1)
            v[k] += __shfl_down(v[k], off);
    }

    __shared__ float sm[(NTHREADS / 64) * 9];
    const int wave = tid >> 6;
    if ((tid & 63) == 0) {
#pragma unroll
        for (int k = 0; k < 9; ++k) sm[wave * 9 + k] = v[k];
    }
    __syncthreads();

    if (tid < 9) {
        float acc = 0.f;
#pragma unroll
        for (int w = 0; w < NTHREADS / 64; ++w) acc += sm[w * 9 + tid];
        // device-visible store (bypasses non-coherent caches)
        __hip_atomic_store(&ws[(size_t)blk * 9 + tid], acc,
                           __ATOMIC_RELAXED, __HIP_MEMORY_SCOPE_AGENT);
    }

    __shared__ unsigned int s_old;
    __syncthreads();   // partial stores happen-before tid0's release-add
    if (tid == 0) {
        s_old = __hip_atomic_fetch_add(&cnt[b], 1u,
                                       __ATOMIC_ACQ_REL, __HIP_MEMORY_SCOPE_AGENT);
    }
    __syncthreads();

    if (s_old == BLOCKS_PER_BATCH - 1) {   // last arrival: all 32 partials visible
        __shared__ float fs[9];
        if (tid < 9) {
            float acc = 0.f;
            const float* base = ws + (size_t)b * BLOCKS_PER_BATCH * 9 + tid;
#pragma unroll
            for (int j = 0; j < BLOCKS_PER_BATCH; ++j)
                acc += __hip_atomic_load(base + (size_t)j * 9,
                                         __ATOMIC_RELAXED, __HIP_MEMORY_SCOPE_AGENT);
            fs[tid] = acc;
        }
        __syncthreads();

        if (tid == 0) {
            const float isg = 1.0f / sigma_sq[0];
            const float il  = 1.0f / lambda_sq[0];

            const float A00 = isg + il * fs[0];
            const float A01 = il * fs[1];
            const float A11 = isg + il * fs[2];
            const float det = A00 * A11 - A01 * A01;
            const float idet = 1.0f / det;
            const float V00 =  A11 * idet;
            const float V01 = -A01 * idet;
            const float V11 =  A00 * idet;

            float* ov = out + 384 + (size_t)b * 4;
            ov[0] = V00; ov[1] = V01; ov[2] = V01; ov[3] = V11;

            const float* M = M_ref + (size_t)b * 6;
            float* om = out + (size_t)b * 6;
#pragma unroll
            for (int si = 0; si < 3; ++si) {
                const float t0 = isg * M[si * 2 + 0] + il * fs[3 + si * 2 + 0];
                const float t1 = isg * M[si * 2 + 1] + il * fs[3 + si * 2 + 1];
                om[si * 2 + 0] = t0 * V00 + t1 * V01;
                om[si * 2 + 1] = t0 * V01 + t1 * V11;
            }
        }
    }
}

extern "C" void kernel_launch(void* const* d_in, const int* in_sizes, int n_in,
                              void* d_out, int out_size, void* d_ws, size_t ws_size,
                              hipStream_t stream) {
    const float* Y      = (const float*)d_in[0];  // (64, 262144, 3)
    const float* C      = (const float*)d_in[1];  // (64, 2, 512, 512)
    const float* M_ref  = (const float*)d_in[2];  // (64, 3, 2)
    const float* sig    = (const float*)d_in[3];
    const float* lam    = (const float*)d_in[4];
    float* out = (float*)d_out;
    float* ws  = (float*)d_ws;
    unsigned int* cnt = (unsigned int*)((char*)d_ws +
                        (size_t)NBATCH * BLOCKS_PER_BATCH * 9 * sizeof(float));

    // counters must be zero at kernel start on EVERY call (graph replays
    // don't re-poison) — tiny 256 B memset, capturable.
    hipMemsetAsync(cnt, 0, NBATCH * sizeof(unsigned int), stream);
    fused_kernel<<<NBATCH * BLOCKS_PER_BATCH, NTHREADS, 0, stream>>>(
        Y, C, M_ref, sig, lam, ws, cnt, out);
}

// Round 3
// 163.301 us; speedup vs baseline: 1.2818x; 1.2818x over previous
//
#include <hip/hip_runtime.h>

#define HW (512 * 512)
#define NBATCH 64
#define BLOCKS_PER_BATCH 32
#define NTHREADS 256
#define PIX_PER_BLOCK (HW / BLOCKS_PER_BATCH)   // 8192
#define NITER (PIX_PER_BLOCK / (NTHREADS * 4))  // 8

// Fused: streaming partial sums + last-block-per-batch finalize.
// NOTE: __launch_bounds__ has NO min-waves clause — R2 showed that forcing
// 8 waves/EU caps VGPRs at 32 and spills the accumulators to scratch
// (137 MB of spill writes, 3.5x slowdown).
__global__ __launch_bounds__(NTHREADS) void fused_kernel(
    const float* __restrict__ Y,      // (B, HW, 3)
    const float* __restrict__ C,      // (B, 2, HW)
    const float* __restrict__ M_ref,  // (B, 3, 2)
    const float* __restrict__ sigma_sq,
    const float* __restrict__ lambda_sq,
    float* __restrict__ ws,           // (B*BLOCKS_PER_BATCH, 9) partials
    unsigned int* __restrict__ cnt,   // (B) arrival counters, memset to 0 per call
    float* __restrict__ out)          // [0:384) out_mean, [384:640) out_var
{
    const int blk = blockIdx.x;
    const int b  = blk / BLOCKS_PER_BATCH;
    const int cb = blk % BLOCKS_PER_BATCH;
    const int tid = threadIdx.x;

    const float* __restrict__ C0 = C + (size_t)b * 2 * HW + (size_t)cb * PIX_PER_BLOCK;
    const float* __restrict__ C1 = C0 + HW;
    const float* __restrict__ Yb = Y + (size_t)b * HW * 3 + (size_t)cb * PIX_PER_BLOCK * 3;

    float g00 = 0.f, g01 = 0.f, g11 = 0.f;
    float y00 = 0.f, y01 = 0.f;
    float y10 = 0.f, y11 = 0.f;
    float y20 = 0.f, y21 = 0.f;

#pragma unroll
    for (int it = 0; it < NITER; ++it) {
        const int p = (it * NTHREADS + tid) * 4;            // pixel group base
        const float4 c0 = *(const float4*)(C0 + p);
        const float4 c1 = *(const float4*)(C1 + p);
        const float4* yv = (const float4*)(Yb + (size_t)p * 3);
        const float4 ya  = yv[0];
        const float4 yb4 = yv[1];
        const float4 yc4 = yv[2];

        g00 += c0.x*c0.x + c0.y*c0.y + c0.z*c0.z + c0.w*c0.w;
        g01 += c0.x*c1.x + c0.y*c1.y + c0.z*c1.z + c0.w*c1.w;
        g11 += c1.x*c1.x + c1.y*c1.y + c1.z*c1.z + c1.w*c1.w;

        // pixel triples: p0:(ya.x,ya.y,ya.z) p1:(ya.w,yb4.x,yb4.y)
        //                p2:(yb4.z,yb4.w,yc4.x) p3:(yc4.y,yc4.z,yc4.w)
        y00 += ya.x*c0.x + ya.w*c0.y + yb4.z*c0.z + yc4.y*c0.w;
        y01 += ya.x*c1.x + ya.w*c1.y + yb4.z*c1.z + yc4.y*c1.w;
        y10 += ya.y*c0.x + yb4.x*c0.y + yb4.w*c0.z + yc4.z*c0.w;
        y11 += ya.y*c1.x + yb4.x*c1.y + yb4.w*c1.z + yc4.z*c1.w;
        y20 += ya.z*c0.x + yb4.y*c0.y + yc4.x*c0.z + yc4.w*c0.w;
        y21 += ya.z*c1.x + yb4.y*c1.y + yc4.x*c1.z + yc4.w*c1.w;
    }

    // wave butterfly reduce the 9 accumulators
    float v[9] = {g00, g01, g11, y00, y01, y10, y11, y20, y21};
#pragma unroll
    for (int k = 0; k < 9; ++k) {
#pragma unroll
        for (int off = 32; off > 0; off >>= 1)
            v[k] += __shfl_down(v[k], off);
    }

    __shared__ float sm[(NTHREADS / 64) * 9];
    const int wave = tid >> 6;
    if ((tid & 63) == 0) {
#pragma unroll
        for (int k = 0; k < 9; ++k) sm[wave * 9 + k] = v[k];
    }
    __syncthreads();

    if (tid < 9) {
        float acc = 0.f;
#pragma unroll
        for (int w = 0; w < NTHREADS / 64; ++w) acc += sm[w * 9 + tid];
        // device-visible store (bypasses non-coherent caches)
        __hip_atomic_store(&ws[(size_t)blk * 9 + tid], acc,
                           __ATOMIC_RELAXED, __HIP_MEMORY_SCOPE_AGENT);
    }

    __shared__ unsigned int s_old;
    __syncthreads();   // partial stores happen-before tid0's release-add
    if (tid == 0) {
        s_old = __hip_atomic_fetch_add(&cnt[b], 1u,
                                       __ATOMIC_ACQ_REL, __HIP_MEMORY_SCOPE_AGENT);
    }
    __syncthreads();

    if (s_old == BLOCKS_PER_BATCH - 1) {   // last arrival: all 32 partials visible
        __shared__ float fs[9];
        if (tid < 9) {
            float acc = 0.f;
            const float* base = ws + (size_t)b * BLOCKS_PER_BATCH * 9 + tid;
#pragma unroll
            for (int j = 0; j < BLOCKS_PER_BATCH; ++j)
                acc += __hip_atomic_load(base + (size_t)j * 9,
                                         __ATOMIC_RELAXED, __HIP_MEMORY_SCOPE_AGENT);
            fs[tid] = acc;
        }
        __syncthreads();

        if (tid == 0) {
            const float isg = 1.0f / sigma_sq[0];
            const float il  = 1.0f / lambda_sq[0];

            const float A00 = isg + il * fs[0];
            const float A01 = il * fs[1];
            const float A11 = isg + il * fs[2];
            const float det = A00 * A11 - A01 * A01;
            const float idet = 1.0f / det;
            const float V00 =  A11 * idet;
            const float V01 = -A01 * idet;
            const float V11 =  A00 * idet;

            float* ov = out + 384 + (size_t)b * 4;
            ov[0] = V00; ov[1] = V01; ov[2] = V01; ov[3] = V11;

            const float* M = M_ref + (size_t)b * 6;
            float* om = out + (size_t)b * 6;
#pragma unroll
            for (int si = 0; si < 3; ++si) {
                const float t0 = isg * M[si * 2 + 0] + il * fs[3 + si * 2 + 0];
                const float t1 = isg * M[si * 2 + 1] + il * fs[3 + si * 2 + 1];
                om[si * 2 + 0] = t0 * V00 + t1 * V01;
                om[si * 2 + 1] = t0 * V01 + t1 * V11;
            }
        }
    }
}

extern "C" void kernel_launch(void* const* d_in, const int* in_sizes, int n_in,
                              void* d_out, int out_size, void* d_ws, size_t ws_size,
                              hipStream_t stream) {
    const float* Y      = (const float*)d_in[0];  // (64, 262144, 3)
    const float* C      = (const float*)d_in[1];  // (64, 2, 512, 512)
    const float* M_ref  = (const float*)d_in[2];  // (64, 3, 2)
    const float* sig    = (const float*)d_in[3];
    const float* lam    = (const float*)d_in[4];
    float* out = (float*)d_out;
    float* ws  = (float*)d_ws;
    unsigned int* cnt = (unsigned int*)((char*)d_ws +
                        (size_t)NBATCH * BLOCKS_PER_BATCH * 9 * sizeof(float));

    // counters must be zero at kernel start on EVERY call (graph replays
    // don't re-poison) — tiny 256 B memset, capturable.
    hipMemsetAsync(cnt, 0, NBATCH * sizeof(unsigned int), stream);
    fused_kernel<<<NBATCH * BLOCKS_PER_BATCH, NTHREADS, 0, stream>>>(
        Y, C, M_ref, sig, lam, ws, cnt, out);
}

// Round 4
// 66.562 us; speedup vs baseline: 3.1447x; 2.4534x over previous
//
#include <hip/hip_runtime.h>

#define HW (512 * 512)
#define NBATCH 64
#define BLOCKS_PER_BATCH 32
#define NTHREADS 256
#define PIX_PER_BLOCK (HW / BLOCKS_PER_BATCH)   // 8192
#define NITER (PIX_PER_BLOCK / (NTHREADS * 4))  // 8

// Fused streaming + last-block finalize.
// R2 lesson: no min-waves clause in __launch_bounds__ (32-VGPR cap -> spills).
// R3 lesson: NO acq_rel on the arrival counter — agent-scope acq_rel emits
// buffer_wbl2 + buffer_inv (full per-XCD L2 writeback+invalidate) in every
// one of 2048 blocks; all blocks finish simultaneously -> ~100us serialized
// L2-maintenance storm. Protocol is correct fully RELAXED because:
//   - partial stores are agent-scope (sc1) atomic stores: bypass the
//     non-coherent L1/L2, land at the device coherence point;
//   - __syncthreads() before the fetch_add drains vmcnt(0); nothing from
//     this kernel is dirty in L2 (all global stores sc1) so no wbl2 needed;
//   - reader loads are control-dependent on the RMW result and below a
//     __syncthreads() (compiler+HW barrier) -> cannot be hoisted; sc1 loads
//     read the coherence point directly, no buffer_inv needed.
__global__ __launch_bounds__(NTHREADS) void fused_kernel(
    const float* __restrict__ Y,      // (B, HW, 3)
    const float* __restrict__ C,      // (B, 2, HW)
    const float* __restrict__ M_ref,  // (B, 3, 2)
    const float* __restrict__ sigma_sq,
    const float* __restrict__ lambda_sq,
    float* __restrict__ ws,           // (B*BLOCKS_PER_BATCH, 9) partials
    unsigned int* __restrict__ cnt,   // (B) arrival counters, zeroed per call
    float* __restrict__ out)          // [0:384) out_mean, [384:640) out_var
{
    const int blk = blockIdx.x;
    const int b  = blk / BLOCKS_PER_BATCH;
    const int cb = blk % BLOCKS_PER_BATCH;
    const int tid = threadIdx.x;

    const float* __restrict__ C0 = C + (size_t)b * 2 * HW + (size_t)cb * PIX_PER_BLOCK;
    const float* __restrict__ C1 = C0 + HW;
    const float* __restrict__ Yb = Y + (size_t)b * HW * 3 + (size_t)cb * PIX_PER_BLOCK * 3;

    float g00 = 0.f, g01 = 0.f, g11 = 0.f;
    float y00 = 0.f, y01 = 0.f;
    float y10 = 0.f, y11 = 0.f;
    float y20 = 0.f, y21 = 0.f;

#pragma unroll
    for (int it = 0; it < NITER; ++it) {
        const int p = (it * NTHREADS + tid) * 4;            // pixel group base
        const float4 c0 = *(const float4*)(C0 + p);
        const float4 c1 = *(const float4*)(C1 + p);
        const float4* yv = (const float4*)(Yb + (size_t)p * 3);
        const float4 ya  = yv[0];
        const float4 yb4 = yv[1];
        const float4 yc4 = yv[2];

        g00 += c0.x*c0.x + c0.y*c0.y + c0.z*c0.z + c0.w*c0.w;
        g01 += c0.x*c1.x + c0.y*c1.y + c0.z*c1.z + c0.w*c1.w;
        g11 += c1.x*c1.x + c1.y*c1.y + c1.z*c1.z + c1.w*c1.w;

        // pixel triples: p0:(ya.x,ya.y,ya.z) p1:(ya.w,yb4.x,yb4.y)
        //                p2:(yb4.z,yb4.w,yc4.x) p3:(yc4.y,yc4.z,yc4.w)
        y00 += ya.x*c0.x + ya.w*c0.y + yb4.z*c0.z + yc4.y*c0.w;
        y01 += ya.x*c1.x + ya.w*c1.y + yb4.z*c1.z + yc4.y*c1.w;
        y10 += ya.y*c0.x + yb4.x*c0.y + yb4.w*c0.z + yc4.z*c0.w;
        y11 += ya.y*c1.x + yb4.x*c1.y + yb4.w*c1.z + yc4.z*c1.w;
        y20 += ya.z*c0.x + yb4.y*c0.y + yc4.x*c0.z + yc4.w*c0.w;
        y21 += ya.z*c1.x + yb4.y*c1.y + yc4.x*c1.z + yc4.w*c1.w;
    }

    // wave butterfly reduce the 9 accumulators
    float v[9] = {g00, g01, g11, y00, y01, y10, y11, y20, y21};
#pragma unroll
    for (int k = 0; k < 9; ++k) {
#pragma unroll
        for (int off = 32; off > 0; off >>= 1)
            v[k] += __shfl_down(v[k], off);
    }

    __shared__ float sm[(NTHREADS / 64) * 9];
    const int wave = tid >> 6;
    if ((tid & 63) == 0) {
#pragma unroll
        for (int k = 0; k < 9; ++k) sm[wave * 9 + k] = v[k];
    }
    __syncthreads();

    if (tid < 9) {
        float acc = 0.f;
#pragma unroll
        for (int w = 0; w < NTHREADS / 64; ++w) acc += sm[w * 9 + tid];
        // agent-scope (sc1) store: bypasses non-coherent caches, lands at
        // the device coherence point. No fence instructions emitted.
        __hip_atomic_store(&ws[(size_t)blk * 9 + tid], acc,
                           __ATOMIC_RELAXED, __HIP_MEMORY_SCOPE_AGENT);
    }

    __shared__ unsigned int s_old;
    __syncthreads();   // drains vmcnt(0): sc1 partial stores globally visible
    if (tid == 0) {
        s_old = __hip_atomic_fetch_add(&cnt[b], 1u,
                                       __ATOMIC_RELAXED, __HIP_MEMORY_SCOPE_AGENT);
    }
    __syncthreads();

    if (s_old == BLOCKS_PER_BATCH - 1) {   // last arrival: all 32 partials visible
        __shared__ float fs[9];
        if (tid < 9) {
            float acc = 0.f;
            const float* base = ws + (size_t)b * BLOCKS_PER_BATCH * 9 + tid;
#pragma unroll
            for (int j = 0; j < BLOCKS_PER_BATCH; ++j)
                acc += __hip_atomic_load(base + (size_t)j * 9,
                                         __ATOMIC_RELAXED, __HIP_MEMORY_SCOPE_AGENT);
            fs[tid] = acc;
        }
        __syncthreads();

        if (tid == 0) {
            const float isg = 1.0f / sigma_sq[0];
            const float il  = 1.0f / lambda_sq[0];

            const float A00 = isg + il * fs[0];
            const float A01 = il * fs[1];
            const float A11 = isg + il * fs[2];
            const float det = A00 * A11 - A01 * A01;
            const float idet = 1.0f / det;
            const float V00 =  A11 * idet;
            const float V01 = -A01 * idet;
            const float V11 =  A00 * idet;

            float* ov = out + 384 + (size_t)b * 4;
            ov[0] = V00; ov[1] = V01; ov[2] = V01; ov[3] = V11;

            const float* M = M_ref + (size_t)b * 6;
            float* om = out + (size_t)b * 6;
#pragma unroll
            for (int si = 0; si < 3; ++si) {
                const float t0 = isg * M[si * 2 + 0] + il * fs[3 + si * 2 + 0];
                const float t1 = isg * M[si * 2 + 1] + il * fs[3 + si * 2 + 1];
                om[si * 2 + 0] = t0 * V00 + t1 * V01;
                om[si * 2 + 1] = t0 * V01 + t1 * V11;
            }
        }
    }
}

extern "C" void kernel_launch(void* const* d_in, const int* in_sizes, int n_in,
                              void* d_out, int out_size, void* d_ws, size_t ws_size,
                              hipStream_t stream) {
    const float* Y      = (const float*)d_in[0];  // (64, 262144, 3)
    const float* C      = (const float*)d_in[1];  // (64, 2, 512, 512)
    const float* M_ref  = (const float*)d_in[2];  // (64, 3, 2)
    const float* sig    = (const float*)d_in[3];
    const float* lam    = (const float*)d_in[4];
    float* out = (float*)d_out;
    float* ws  = (float*)d_ws;
    unsigned int* cnt = (unsigned int*)((char*)d_ws +
                        (size_t)NBATCH * BLOCKS_PER_BATCH * 9 * sizeof(float));

    // counters must be zero at kernel start on EVERY call (graph replays
    // don't re-poison) — tiny 256 B memset, capturable.
    hipMemsetAsync(cnt, 0, NBATCH * sizeof(unsigned int), stream);
    fused_kernel<<<NBATCH * BLOCKS_PER_BATCH, NTHREADS, 0, stream>>>(
        Y, C, M_ref, sig, lam, ws, cnt, out);
}

// Round 5
// 66.017 us; speedup vs baseline: 3.1706x; 1.0083x over previous
//
#include <hip/hip_runtime.h>

#define HW (512 * 512)
#define NBATCH 64
#define BLOCKS_PER_BATCH 32
#define NTHREADS 256
#define PIX_PER_BLOCK (HW / BLOCKS_PER_BATCH)   // 8192
#define NITER (PIX_PER_BLOCK / (NTHREADS * 4))  // 8
#define CNT_STRIDE 32   // pad arrival counters to one per 128 B cacheline

// Fused streaming + last-block finalize.
// R2 lesson: no min-waves clause in __launch_bounds__ (32-VGPR cap -> spills).
// R3 lesson: no acq_rel on the arrival counter (per-XCD L2 wb/inv storm).
// R4 lesson: contiguous counters share cachelines -> up to 512 serialized
//            agent-scope RMWs per line at the coherence point (~8-12us tail).
//            Pad to one counter per 128 B line: 32 RMWs/line, 64 lines parallel.
__global__ __launch_bounds__(NTHREADS) void fused_kernel(
    const float* __restrict__ Y,      // (B, HW, 3)
    const float* __restrict__ C,      // (B, 2, HW)
    const float* __restrict__ M_ref,  // (B, 3, 2)
    const float* __restrict__ sigma_sq,
    const float* __restrict__ lambda_sq,
    float* __restrict__ ws,           // (B*BLOCKS_PER_BATCH, 9) partials
    unsigned int* __restrict__ cnt,   // (B*CNT_STRIDE) padded counters, zeroed per call
    float* __restrict__ out)          // [0:384) out_mean, [384:640) out_var
{
    const int blk = blockIdx.x;
    const int b  = blk / BLOCKS_PER_BATCH;
    const int cb = blk % BLOCKS_PER_BATCH;
    const int tid = threadIdx.x;

    const float* __restrict__ C0 = C + (size_t)b * 2 * HW + (size_t)cb * PIX_PER_BLOCK;
    const float* __restrict__ C1 = C0 + HW;
    const float* __restrict__ Yb = Y + (size_t)b * HW * 3 + (size_t)cb * PIX_PER_BLOCK * 3;

    float g00 = 0.f, g01 = 0.f, g11 = 0.f;
    float y00 = 0.f, y01 = 0.f;
    float y10 = 0.f, y11 = 0.f;
    float y20 = 0.f, y21 = 0.f;

#pragma unroll
    for (int it = 0; it < NITER; ++it) {
        const int p = (it * NTHREADS + tid) * 4;            // pixel group base
        const float4 c0 = *(const float4*)(C0 + p);
        const float4 c1 = *(const float4*)(C1 + p);
        const float4* yv = (const float4*)(Yb + (size_t)p * 3);
        const float4 ya  = yv[0];
        const float4 yb4 = yv[1];
        const float4 yc4 = yv[2];

        g00 += c0.x*c0.x + c0.y*c0.y + c0.z*c0.z + c0.w*c0.w;
        g01 += c0.x*c1.x + c0.y*c1.y + c0.z*c1.z + c0.w*c1.w;
        g11 += c1.x*c1.x + c1.y*c1.y + c1.z*c1.z + c1.w*c1.w;

        // pixel triples: p0:(ya.x,ya.y,ya.z) p1:(ya.w,yb4.x,yb4.y)
        //                p2:(yb4.z,yb4.w,yc4.x) p3:(yc4.y,yc4.z,yc4.w)
        y00 += ya.x*c0.x + ya.w*c0.y + yb4.z*c0.z + yc4.y*c0.w;
        y01 += ya.x*c1.x + ya.w*c1.y + yb4.z*c1.z + yc4.y*c1.w;
        y10 += ya.y*c0.x + yb4.x*c0.y + yb4.w*c0.z + yc4.z*c0.w;
        y11 += ya.y*c1.x + yb4.x*c1.y + yb4.w*c1.z + yc4.z*c1.w;
        y20 += ya.z*c0.x + yb4.y*c0.y + yc4.x*c0.z + yc4.w*c0.w;
        y21 += ya.z*c1.x + yb4.y*c1.y + yc4.x*c1.z + yc4.w*c1.w;
    }

    // wave butterfly reduce the 9 accumulators
    float v[9] = {g00, g01, g11, y00, y01, y10, y11, y20, y21};
#pragma unroll
    for (int k = 0; k < 9; ++k) {
#pragma unroll
        for (int off = 32; off > 0; off >>= 1)
            v[k] += __shfl_down(v[k], off);
    }

    __shared__ float sm[(NTHREADS / 64) * 9];
    const int wave = tid >> 6;
    if ((tid & 63) == 0) {
#pragma unroll
        for (int k = 0; k < 9; ++k) sm[wave * 9 + k] = v[k];
    }
    __syncthreads();

    if (tid < 9) {
        float acc = 0.f;
#pragma unroll
        for (int w = 0; w < NTHREADS / 64; ++w) acc += sm[w * 9 + tid];
        // agent-scope (sc1) store: bypasses non-coherent caches, lands at
        // the device coherence point. No fence instructions emitted.
        __hip_atomic_store(&ws[(size_t)blk * 9 + tid], acc,
                           __ATOMIC_RELAXED, __HIP_MEMORY_SCOPE_AGENT);
    }

    __shared__ unsigned int s_old;
    __syncthreads();   // drains vmcnt(0): sc1 partial stores globally visible
    if (tid == 0) {
        s_old = __hip_atomic_fetch_add(&cnt[(size_t)b * CNT_STRIDE], 1u,
                                       __ATOMIC_RELAXED, __HIP_MEMORY_SCOPE_AGENT);
    }
    __syncthreads();

    if (s_old == BLOCKS_PER_BATCH - 1) {   // last arrival: all 32 partials visible
        __shared__ float fs[9];
        if (tid < 9) {
            float acc = 0.f;
            const float* base = ws + (size_t)b * BLOCKS_PER_BATCH * 9 + tid;
#pragma unroll
            for (int j = 0; j < BLOCKS_PER_BATCH; ++j)
                acc += __hip_atomic_load(base + (size_t)j * 9,
                                         __ATOMIC_RELAXED, __HIP_MEMORY_SCOPE_AGENT);
            fs[tid] = acc;
        }
        __syncthreads();

        if (tid == 0) {
            const float isg = 1.0f / sigma_sq[0];
            const float il  = 1.0f / lambda_sq[0];

            const float A00 = isg + il * fs[0];
            const float A01 = il * fs[1];
            const float A11 = isg + il * fs[2];
            const float det = A00 * A11 - A01 * A01;
            const float idet = 1.0f / det;
            const float V00 =  A11 * idet;
            const float V01 = -A01 * idet;
            const float V11 =  A00 * idet;

            float* ov = out + 384 + (size_t)b * 4;
            ov[0] = V00; ov[1] = V01; ov[2] = V01; ov[3] = V11;

            const float* M = M_ref + (size_t)b * 6;
            float* om = out + (size_t)b * 6;
#pragma unroll
            for (int si = 0; si < 3; ++si) {
                const float t0 = isg * M[si * 2 + 0] + il * fs[3 + si * 2 + 0];
                const float t1 = isg * M[si * 2 + 1] + il * fs[3 + si * 2 + 1];
                om[si * 2 + 0] = t0 * V00 + t1 * V01;
                om[si * 2 + 1] = t0 * V01 + t1 * V11;
            }
        }
    }
}

extern "C" void kernel_launch(void* const* d_in, const int* in_sizes, int n_in,
                              void* d_out, int out_size, void* d_ws, size_t ws_size,
                              hipStream_t stream) {
    const float* Y      = (const float*)d_in[0];  // (64, 262144, 3)
    const float* C      = (const float*)d_in[1];  // (64, 2, 512, 512)
    const float* M_ref  = (const float*)d_in[2];  // (64, 3, 2)
    const float* sig    = (const float*)d_in[3];
    const float* lam    = (const float*)d_in[4];
    float* out = (float*)d_out;
    float* ws  = (float*)d_ws;
    unsigned int* cnt = (unsigned int*)((char*)d_ws +
                        (size_t)NBATCH * BLOCKS_PER_BATCH * 9 * sizeof(float));

    // counters must be zero at kernel start on EVERY call (graph replays
    // don't re-poison) — 8 KB memset, capturable.
    hipMemsetAsync(cnt, 0, (size_t)NBATCH * CNT_STRIDE * sizeof(unsigned int), stream);
    fused_kernel<<<NBATCH * BLOCKS_PER_BATCH, NTHREADS, 0, stream>>>(
        Y, C, M_ref, sig, lam, ws, cnt, out);
}

// Round 6
// 60.451 us; speedup vs baseline: 3.4626x; 1.0921x over previous
//
#include <hip/hip_runtime.h>

#define HW (512 * 512)
#define NBATCH 64
#define BLOCKS_PER_BATCH 32
#define NTHREADS 256
#define PIX_PER_BLOCK (HW / BLOCKS_PER_BATCH)   // 8192
#define PIX_PER_ITER (NTHREADS * 4)             // 1024
#define NITER (PIX_PER_BLOCK / PIX_PER_ITER)    // 8
#define Y4_PER_ITER (PIX_PER_ITER * 3 / 4)      // 768 float4 of Y per iter

// Kernel 1: streaming partial sums. Y is staged through a double-buffered
// LDS tile so the global Y loads are lane-linear float4 (perfectly
// coalesced) instead of 48-byte-stride. C loads stay direct (already
// perfectly coalesced). Reduction + plain stores as in R1.
__global__ __launch_bounds__(NTHREADS) void partials_kernel(
    const float* __restrict__ Y,   // (B, HW, 3)
    const float* __restrict__ C,   // (B, 2, HW)
    float* __restrict__ ws)        // (B*BLOCKS_PER_BATCH, 9)
{
    const int blk = blockIdx.x;
    const int b  = blk / BLOCKS_PER_BATCH;
    const int cb = blk % BLOCKS_PER_BATCH;
    const int tid = threadIdx.x;

    const float* __restrict__ C0 = C + (size_t)b * 2 * HW + (size_t)cb * PIX_PER_BLOCK;
    const float* __restrict__ C1 = C0 + HW;
    const float4* __restrict__ Yb4 =
        (const float4*)(Y + (size_t)b * HW * 3 + (size_t)cb * PIX_PER_BLOCK * 3);

    __shared__ float4 ybuf[2][Y4_PER_ITER];   // 2 x 12 KB

    // stage iter 0
    {
        const float4* src = Yb4;
        ybuf[0][tid]       = src[tid];
        ybuf[0][tid + 256] = src[tid + 256];
        ybuf[0][tid + 512] = src[tid + 512];
    }
    __syncthreads();

    float g00 = 0.f, g01 = 0.f, g11 = 0.f;
    float y00 = 0.f, y01 = 0.f;
    float y10 = 0.f, y11 = 0.f;
    float y20 = 0.f, y21 = 0.f;

#pragma unroll
    for (int it = 0; it < NITER; ++it) {
        const int cur = it & 1;
        // prefetch next iter's Y tile into the other buffer (coalesced)
        if (it + 1 < NITER) {
            const float4* src = Yb4 + (size_t)(it + 1) * Y4_PER_ITER;
            ybuf[cur ^ 1][tid]       = src[tid];
            ybuf[cur ^ 1][tid + 256] = src[tid + 256];
            ybuf[cur ^ 1][tid + 512] = src[tid + 512];
        }

        const int p = (it * NTHREADS + tid) * 4;            // pixel group base
        const float4 c0 = *(const float4*)(C0 + p);
        const float4 c1 = *(const float4*)(C1 + p);
        // thread's 4 pixel triples from LDS: float4s [3t, 3t+3)
        const float4 ya  = ybuf[cur][3 * tid + 0];
        const float4 yb4 = ybuf[cur][3 * tid + 1];
        const float4 yc4 = ybuf[cur][3 * tid + 2];

        g00 += c0.x*c0.x + c0.y*c0.y + c0.z*c0.z + c0.w*c0.w;
        g01 += c0.x*c1.x + c0.y*c1.y + c0.z*c1.z + c0.w*c1.w;
        g11 += c1.x*c1.x + c1.y*c1.y + c1.z*c1.z + c1.w*c1.w;

        // pixel triples: p0:(ya.x,ya.y,ya.z) p1:(ya.w,yb4.x,yb4.y)
        //                p2:(yb4.z,yb4.w,yc4.x) p3:(yc4.y,yc4.z,yc4.w)
        y00 += ya.x*c0.x + ya.w*c0.y + yb4.z*c0.z + yc4.y*c0.w;
        y01 += ya.x*c1.x + ya.w*c1.y + yb4.z*c1.z + yc4.y*c1.w;
        y10 += ya.y*c0.x + yb4.x*c0.y + yb4.w*c0.z + yc4.z*c0.w;
        y11 += ya.y*c1.x + yb4.x*c1.y + yb4.w*c1.z + yc4.z*c1.w;
        y20 += ya.z*c0.x + yb4.y*c0.y + yc4.x*c0.z + yc4.w*c0.w;
        y21 += ya.z*c1.x + yb4.y*c1.y + yc4.x*c1.z + yc4.w*c1.w;

        __syncthreads();   // all reads of ybuf[cur] done before it is re-staged
    }

    // wave (64-lane) butterfly reduce all 9 values
    float v[9] = {g00, g01, g11, y00, y01, y10, y11, y20, y21};
#pragma unroll
    for (int k = 0; k < 9; ++k) {
#pragma unroll
        for (int off = 32; off > 0; off >>= 1)
            v[k] += __shfl_down(v[k], off);
    }

    __shared__ float sm[(NTHREADS / 64) * 9];
    const int wave = tid >> 6;
    if ((tid & 63) == 0) {
#pragma unroll
        for (int k = 0; k < 9; ++k) sm[wave * 9 + k] = v[k];
    }
    __syncthreads();

    if (tid < 9) {
        float acc = 0.f;
#pragma unroll
        for (int w = 0; w < NTHREADS / 64; ++w) acc += sm[w * 9 + tid];
        ws[(size_t)blk * 9 + tid] = acc;
    }
}

// Kernel 2: per-batch final reduce + 2x2 inverse + (3,2)@(2,2) epilogue.
__global__ __launch_bounds__(64) void finalize_kernel(
    const float* __restrict__ ws,     // (B*BLOCKS_PER_BATCH, 9)
    const float* __restrict__ M_ref,  // (B, 3, 2)
    const float* __restrict__ sigma_sq,
    const float* __restrict__ lambda_sq,
    float* __restrict__ out)          // [0:384) out_mean (B,3,2), [384:640) out_var (B,2,2)
{
    const int b = blockIdx.x;
    const int tid = threadIdx.x;
    __shared__ float s[9];

    if (tid < 9) {
        float acc = 0.f;
        const float* base = ws + (size_t)b * BLOCKS_PER_BATCH * 9 + tid;
#pragma unroll
        for (int j = 0; j < BLOCKS_PER_BATCH; ++j) acc += base[(size_t)j * 9];
        s[tid] = acc;
    }
    __syncthreads();

    if (tid == 0) {
        const float isg = 1.0f / sigma_sq[0];
        const float il  = 1.0f / lambda_sq[0];

        const float A00 = isg + il * s[0];
        const float A01 = il * s[1];
        const float A11 = isg + il * s[2];
        const float det = A00 * A11 - A01 * A01;
        const float idet = 1.0f / det;
        const float V00 =  A11 * idet;
        const float V01 = -A01 * idet;
        const float V11 =  A00 * idet;

        // out_var (B,2,2)
        float* ov = out + 384 + (size_t)b * 4;
        ov[0] = V00; ov[1] = V01; ov[2] = V01; ov[3] = V11;

        // out_mean (B,3,2): T = isg*M_ref + il*yc ; out = T @ V
        const float* M = M_ref + (size_t)b * 6;
        float* om = out + (size_t)b * 6;
#pragma unroll
        for (int si = 0; si < 3; ++si) {
            const float t0 = isg * M[si * 2 + 0] + il * s[3 + si * 2 + 0];
            const float t1 = isg * M[si * 2 + 1] + il * s[3 + si * 2 + 1];
            om[si * 2 + 0] = t0 * V00 + t1 * V01;
            om[si * 2 + 1] = t0 * V01 + t1 * V11;
        }
    }
}

extern "C" void kernel_launch(void* const* d_in, const int* in_sizes, int n_in,
                              void* d_out, int out_size, void* d_ws, size_t ws_size,
                              hipStream_t stream) {
    const float* Y      = (const float*)d_in[0];  // (64, 262144, 3)
    const float* C      = (const float*)d_in[1];  // (64, 2, 512, 512)
    const float* M_ref  = (const float*)d_in[2];  // (64, 3, 2)
    const float* sig    = (const float*)d_in[3];
    const float* lam    = (const float*)d_in[4];
    float* out = (float*)d_out;
    float* ws  = (float*)d_ws;                    // B*32*9*4 = 73728 bytes

    partials_kernel<<<NBATCH * BLOCKS_PER_BATCH, NTHREADS, 0, stream>>>(Y, C, ws);
    finalize_kernel<<<NBATCH, 64, 0, stream>>>(ws, M_ref, sig, lam, out);
}

// Round 7
// 58.858 us; speedup vs baseline: 3.5563x; 1.0271x over previous
//
#include <hip/hip_runtime.h>

#define HW (512 * 512)
#define NBATCH 64
#define BLOCKS_PER_BATCH 32
#define NTHREADS 256
#define PIX_PER_BLOCK (HW / BLOCKS_PER_BATCH)   // 8192
#define PIX_PER_ITER (NTHREADS * 4)             // 1024
#define NITER (PIX_PER_BLOCK / PIX_PER_ITER)    // 8

// R1 form — the empirical winner:
//   R2-R5: fused last-block-finalize variants all slower (66.6/66.0 us);
//          agent-scope RMW/fence tails cost more than the 2nd dispatch.
//   R6:    LDS-staging Y slower (60.5 us): 48B-stride float4 loads are
//          already fully coalesced (dense 3KB span/wave), and the staging
//          added 1.3M LDS bank conflicts + occupancy cap.
// Kernel 1: per-(batch, chunk) partial sums of the 9 accumulators:
//   g00, g01, g11  (gram, symmetric 2x2)
//   yc[s][n] for s in 0..2, n in 0..1
__global__ __launch_bounds__(NTHREADS) void partials_kernel(
    const float* __restrict__ Y,   // (B, HW, 3)
    const float* __restrict__ C,   // (B, 2, HW)
    float* __restrict__ ws)        // (B*BLOCKS_PER_BATCH, 9)
{
    const int blk = blockIdx.x;
    const int b  = blk / BLOCKS_PER_BATCH;
    const int cb = blk % BLOCKS_PER_BATCH;
    const int tid = threadIdx.x;

    const float* __restrict__ C0 = C + (size_t)b * 2 * HW + (size_t)cb * PIX_PER_BLOCK;
    const float* __restrict__ C1 = C0 + HW;
    const float* __restrict__ Yb = Y + (size_t)b * HW * 3 + (size_t)cb * PIX_PER_BLOCK * 3;

    float g00 = 0.f, g01 = 0.f, g11 = 0.f;
    float y00 = 0.f, y01 = 0.f;   // yc[0][0], yc[0][1]
    float y10 = 0.f, y11 = 0.f;   // yc[1][0], yc[1][1]
    float y20 = 0.f, y21 = 0.f;   // yc[2][0], yc[2][1]

#pragma unroll
    for (int it = 0; it < NITER; ++it) {
        const int p = (it * NTHREADS + tid) * 4;            // pixel group base
        const float4 c0 = *(const float4*)(C0 + p);
        const float4 c1 = *(const float4*)(C1 + p);
        const float4* yv = (const float4*)(Yb + (size_t)p * 3);
        const float4 ya = yv[0];
        const float4 yb4 = yv[1];
        const float4 yc4 = yv[2];

        // gram
        g00 += c0.x*c0.x + c0.y*c0.y + c0.z*c0.z + c0.w*c0.w;
        g01 += c0.x*c1.x + c0.y*c1.y + c0.z*c1.z + c0.w*c1.w;
        g11 += c1.x*c1.x + c1.y*c1.y + c1.z*c1.z + c1.w*c1.w;

        // yc: pixel k's Y triple:
        //  p0: ya.x, ya.y, ya.z
        //  p1: ya.w, yb4.x, yb4.y
        //  p2: yb4.z, yb4.w, yc4.x
        //  p3: yc4.y, yc4.z, yc4.w
        y00 += ya.x*c0.x + ya.w*c0.y + yb4.z*c0.z + yc4.y*c0.w;
        y01 += ya.x*c1.x + ya.w*c1.y + yb4.z*c1.z + yc4.y*c1.w;
        y10 += ya.y*c0.x + yb4.x*c0.y + yb4.w*c0.z + yc4.z*c0.w;
        y11 += ya.y*c1.x + yb4.x*c1.y + yb4.w*c1.z + yc4.z*c1.w;
        y20 += ya.z*c0.x + yb4.y*c0.y + yc4.x*c0.z + yc4.w*c0.w;
        y21 += ya.z*c1.x + yb4.y*c1.y + yc4.x*c1.z + yc4.w*c1.w;
    }

    // wave (64-lane) butterfly reduce all 9 values
    float v[9] = {g00, g01, g11, y00, y01, y10, y11, y20, y21};
#pragma unroll
    for (int k = 0; k < 9; ++k) {
#pragma unroll
        for (int off = 32; off > 0; off >>= 1)
            v[k] += __shfl_down(v[k], off);
    }

    __shared__ float sm[(NTHREADS / 64) * 9];
    const int wave = tid >> 6;
    if ((tid & 63) == 0) {
#pragma unroll
        for (int k = 0; k < 9; ++k) sm[wave * 9 + k] = v[k];
    }
    __syncthreads();

    if (tid < 9) {
        float acc = 0.f;
#pragma unroll
        for (int w = 0; w < NTHREADS / 64; ++w) acc += sm[w * 9 + tid];
        ws[(size_t)blk * 9 + tid] = acc;
    }
}

// Kernel 2: per-batch final reduce + 2x2 inverse + (3,2)@(2,2) epilogue.
__global__ __launch_bounds__(64) void finalize_kernel(
    const float* __restrict__ ws,     // (B*BLOCKS_PER_BATCH, 9)
    const float* __restrict__ M_ref,  // (B, 3, 2)
    const float* __restrict__ sigma_sq,
    const float* __restrict__ lambda_sq,
    float* __restrict__ out)          // [0:384) out_mean (B,3,2), [384:640) out_var (B,2,2)
{
    const int b = blockIdx.x;
    const int tid = threadIdx.x;
    __shared__ float s[9];

    if (tid < 9) {
        float acc = 0.f;
        const float* base = ws + (size_t)b * BLOCKS_PER_BATCH * 9 + tid;
#pragma unroll
        for (int j = 0; j < BLOCKS_PER_BATCH; ++j) acc += base[(size_t)j * 9];
        s[tid] = acc;
    }
    __syncthreads();

    if (tid == 0) {
        const float isg = 1.0f / sigma_sq[0];
        const float il  = 1.0f / lambda_sq[0];

        const float A00 = isg + il * s[0];
        const float A01 = il * s[1];
        const float A11 = isg + il * s[2];
        const float det = A00 * A11 - A01 * A01;
        const float idet = 1.0f / det;
        const float V00 =  A11 * idet;
        const float V01 = -A01 * idet;
        const float V11 =  A00 * idet;

        // out_var (B,2,2)
        float* ov = out + 384 + (size_t)b * 4;
        ov[0] = V00; ov[1] = V01; ov[2] = V01; ov[3] = V11;

        // out_mean (B,3,2): T = isg*M_ref + il*yc ; out = T @ V
        const float* M = M_ref + (size_t)b * 6;
        float* om = out + (size_t)b * 6;
#pragma unroll
        for (int si = 0; si < 3; ++si) {
            const float t0 = isg * M[si * 2 + 0] + il * s[3 + si * 2 + 0];
            const float t1 = isg * M[si * 2 + 1] + il * s[3 + si * 2 + 1];
            om[si * 2 + 0] = t0 * V00 + t1 * V01;
            om[si * 2 + 1] = t0 * V01 + t1 * V11;
        }
    }
}

extern "C" void kernel_launch(void* const* d_in, const int* in_sizes, int n_in,
                              void* d_out, int out_size, void* d_ws, size_t ws_size,
                              hipStream_t stream) {
    const float* Y      = (const float*)d_in[0];  // (64, 262144, 3)
    const float* C      = (const float*)d_in[1];  // (64, 2, 512, 512)
    const float* M_ref  = (const float*)d_in[2];  // (64, 3, 2)
    const float* sig    = (const float*)d_in[3];  // scalar
    const float* lam    = (const float*)d_in[4];  // scalar
    float* out = (float*)d_out;
    float* ws  = (float*)d_ws;                    // needs B*32*9*4 = 73728 bytes

    partials_kernel<<<NBATCH * BLOCKS_PER_BATCH, NTHREADS, 0, stream>>>(Y, C, ws);
    finalize_kernel<<<NBATCH, 64, 0, stream>>>(ws, M_ref, sig, lam, out);
}